// Round 8
// baseline (227.785 us; speedup 1.0000x reference)
//
#include <hip/hip_runtime.h>
#include <stdint.h>

typedef __attribute__((ext_vector_type(8)))  short  short8;
typedef __attribute__((ext_vector_type(8)))  __bf16 bf16x8;
typedef __attribute__((ext_vector_type(16))) float  floatx16;
typedef __attribute__((ext_vector_type(4)))  float  floatx4;
typedef __attribute__((ext_vector_type(2)))  float  float2v;
typedef __attribute__((ext_vector_type(4)))  uint32_t uint4v;

union Frag { short8 s; bf16x8 v; uint4v d; };
union FU   { float f; uint32_t u; };

// round-to-nearest-even f32 -> bf16 (setup only)
__device__ __forceinline__ short f2bf(float f) {
    FU x; x.f = f;
    uint32_t r = x.u + 0x7fffu + ((x.u >> 16) & 1u);
    return (short)(r >> 16);
}

// pack two f32 -> bf16x2 dword, round-half-up: 2 adds + 1 v_perm
__device__ __forceinline__ uint32_t pack_bf2(float lo, float hi) {
    FU a, b; a.f = lo; b.f = hi;
    return __builtin_amdgcn_perm(b.u + 0x8000u, a.u + 0x8000u, 0x07060302u);
}

__device__ __forceinline__ float fexp2(float x) { return __builtin_amdgcn_exp2f(x); }
__device__ __forceinline__ float frcp(float x)  { return __builtin_amdgcn_rcpf(x); }
__device__ __forceinline__ float fclamp(float x, float lo, float hi) {
#if __has_builtin(__builtin_amdgcn_fmed3f)
    return __builtin_amdgcn_fmed3f(x, lo, hi);
#else
    return fminf(fmaxf(x, lo), hi);
#endif
}

// T = exp2(clamp(arg)) + 1 for the (acc0[r], acc1[r]) pair (pk_add for +1)
__device__ __forceinline__ float2v tpair(float a, float b) {
    float2v t;
    t.x = fexp2(fclamp(a, -30.0f, 30.0f));
    t.y = fexp2(fclamp(b, -30.0f, 30.0f));
    return t + 1.0f;
}

// y[b] = a0 + sum_k bk[k] * tanh(ck[k,:].z[b,:] + dk[k])
//
// Same math/structure as R7 (straight-line 4 tiles/wave, MFMA 32x32x16,
// 4-way shared-denominator exp2 tanh).
//
// R8 DIAGNOSTIC: nrep=2 identical passes (pass 2 L3-warm). Purpose: push
// the dispatch over the 77us fill kernels so it surfaces in rocprof top-5
// -- R1..R7 single-pass kernels never did, leaving VGPR/Occupancy/VALUBusy
// for this structure unknown and 4 predictions in a row wrong. rep_off is
// a RUNTIME zero so the compiler cannot CSE pass-2's loads into pass-1's
// registers. Decision rules: VALUBusy>=78% => cold pass is VALU-dense
// (next: kill trans ops); <=65% => latency-stalled (next: occupancy/LDS).
__global__ __launch_bounds__(256) void mave_kernel(
    const float* __restrict__ z,
    const float* __restrict__ a0,
    const float* __restrict__ bk,
    const float* __restrict__ ck,
    const float* __restrict__ dk,
    float* __restrict__ out,
    int ntiles, int nrep, long long rep_off)
{
    const int lane = threadIdx.x & 63;
    const int m    = lane & 31;
    const int g    = lane >> 5;
    const float S  = 2.885390081777927f;  // 2*log2(e)

    const int wid   = (int)((blockIdx.x * blockDim.x + threadIdx.x) >> 6);
    const int tile0 = wid * 4;
    if (tile0 >= ntiles) return;
    const int tlast = ntiles - 1;

    // ---- preamble (once) ----
    Frag af0, af1;
    {
        const float* c0 = ck + m * 16 + g * 8;
        const float* c1 = c0 + 32 * 16;
        #pragma unroll
        for (int e = 0; e < 8; ++e) {
            af0.s[e] = f2bf(c0[e] * S);
            af1.s[e] = f2bf(c1[e] * S);
        }
    }
    floatx16 cinit0, cinit1;
    uint32_t nbp[16];
    #pragma unroll
    for (int r = 0; r < 16; ++r) {
        int n = (r & 3) + 8 * (r >> 2) + 4 * g;
        cinit0[r] = S * dk[n];
        cinit1[r] = S * dk[n + 32];
        nbp[r] = pack_bf2(-2.0f * bk[n], -2.0f * bk[n + 32]);
    }
    float base = a0[0];
    for (int k = 0; k < 64; ++k) base += bk[k];

    #pragma unroll 1
    for (int rep = 0; rep < nrep; ++rep) {
        // rep_off == 0 at runtime; defeats cross-pass load CSE
        const float* zr = z + (size_t)rep * (size_t)rep_off;

        // ---- all 8 dwordx4 z loads up front (monotone vmcnt) ----
        floatx4 zb[4][2];
        {
            const float* zp = zr + (size_t)m * 16 + g * 8;
            #pragma unroll
            for (int i = 0; i < 4; ++i) {
                int ti = tile0 + i; if (ti > tlast) ti = tlast;
                const float* q = zp + (size_t)ti * 512;
                zb[i][0] = *(const floatx4*)q;
                zb[i][1] = *(const floatx4*)(q + 4);
            }
        }

        // ---- consume in load order ----
        #pragma unroll
        for (int i = 0; i < 4; ++i) {
            Frag bfr;
            bfr.d[0] = pack_bf2(zb[i][0].x, zb[i][0].y);
            bfr.d[1] = pack_bf2(zb[i][0].z, zb[i][0].w);
            bfr.d[2] = pack_bf2(zb[i][1].x, zb[i][1].y);
            bfr.d[3] = pack_bf2(zb[i][1].z, zb[i][1].w);

            floatx16 acc0 = __builtin_amdgcn_mfma_f32_32x32x16_bf16(af0.v, bfr.v, cinit0, 0, 0, 0);
            floatx16 acc1 = __builtin_amdgcn_mfma_f32_32x32x16_bf16(af1.v, bfr.v, cinit1, 0, 0, 0);

            float2v Ya = {0.0f, 0.0f}, Yb = {0.0f, 0.0f};
            #pragma unroll
            for (int r = 0; r < 16; r += 4) {
                float2v T0 = tpair(acc0[r+0], acc1[r+0]);
                float2v T1 = tpair(acc0[r+1], acc1[r+1]);
                float2v T2 = tpair(acc0[r+2], acc1[r+2]);
                float2v T3 = tpair(acc0[r+3], acc1[r+3]);
                float2v P01 = T0 * T1, P23 = T2 * T3, P = P01 * P23;
                float2v R; R.x = frcp(P.x); R.y = frcp(P.y);
                FU l0, h0, l1, h1, l2, h2, l3, h3;
                l0.u = nbp[r+0] << 16; h0.u = nbp[r+0] & 0xffff0000u;
                l1.u = nbp[r+1] << 16; h1.u = nbp[r+1] & 0xffff0000u;
                l2.u = nbp[r+2] << 16; h2.u = nbp[r+2] & 0xffff0000u;
                l3.u = nbp[r+3] << 16; h3.u = nbp[r+3] & 0xffff0000u;
                float2v nb0 = {l0.f, h0.f}, nb1 = {l1.f, h1.f};
                float2v nb2 = {l2.f, h2.f}, nb3 = {l3.f, h3.f};
                float2v n01 = nb0 * T1 + nb1 * T0;
                float2v n23 = nb2 * T3 + nb3 * T2;
                float2v num = n01 * P23 + n23 * P01;
                if (r & 4) Yb += num * R; else Ya += num * R;
            }
            float2v Yv = Ya + Yb;
            float y = Yv.x + Yv.y;
            y += __shfl_xor(y, 32, 64);
            int ti = tile0 + i; if (ti > tlast) ti = tlast;
            if (g == 0) out[ti * 32 + m] = base + y;
        }
    }
}

extern "C" void kernel_launch(void* const* d_in, const int* in_sizes, int n_in,
                              void* d_out, int out_size, void* d_ws, size_t ws_size,
                              hipStream_t stream) {
    const float* z  = (const float*)d_in[0];
    const float* a0 = (const float*)d_in[1];
    const float* bk = (const float*)d_in[2];
    const float* ck = (const float*)d_in[3];
    const float* dk = (const float*)d_in[4];
    float* out = (float*)d_out;

    const int B      = in_sizes[0] / 16;       // z is [B,16]
    const int ntiles = B / 32;                 // 32 batch rows per wave-tile

    const int blocks = (ntiles + 15) / 16;     // 4 waves x 4 tiles per block
    hipLaunchKernelGGL(mave_kernel, dim3(blocks), dim3(256), 0, stream,
                       z, a0, bk, ck, dk, out, ntiles,
                       /*nrep=*/2, /*rep_off=*/(long long)0);
}

// Round 9
// 198.121 us; speedup vs baseline: 1.1497x; 1.1497x over previous
//
#include <hip/hip_runtime.h>
#include <stdint.h>

typedef __attribute__((ext_vector_type(8)))  short  short8;
typedef __attribute__((ext_vector_type(8)))  __bf16 bf16x8;
typedef __attribute__((ext_vector_type(16))) float  floatx16;
typedef __attribute__((ext_vector_type(4)))  float  floatx4;
typedef __attribute__((ext_vector_type(2)))  float  float2v;
typedef __attribute__((ext_vector_type(4)))  uint32_t uint4v;

union Frag { short8 s; bf16x8 v; uint4v d; };
union FU   { float f; uint32_t u; };

// round-to-nearest-even f32 -> bf16 (setup only)
__device__ __forceinline__ short f2bf(float f) {
    FU x; x.f = f;
    uint32_t r = x.u + 0x7fffu + ((x.u >> 16) & 1u);
    return (short)(r >> 16);
}

// pack two f32 -> bf16x2 dword, round-half-up: 2 adds + 1 v_perm
__device__ __forceinline__ uint32_t pack_bf2(float lo, float hi) {
    FU a, b; a.f = lo; b.f = hi;
    return __builtin_amdgcn_perm(b.u + 0x8000u, a.u + 0x8000u, 0x07060302u);
}

__device__ __forceinline__ float fexp2(float x) { return __builtin_amdgcn_exp2f(x); }
__device__ __forceinline__ float frcp(float x)  { return __builtin_amdgcn_rcpf(x); }
__device__ __forceinline__ float fclamp(float x, float lo, float hi) {
#if __has_builtin(__builtin_amdgcn_fmed3f)
    return __builtin_amdgcn_fmed3f(x, lo, hi);
#else
    return fminf(fmaxf(x, lo), hi);
#endif
}

// T = exp2(clamp(arg)) + 1 for the (acc0[r], acc1[r]) pair
__device__ __forceinline__ float2v tpair(float a, float b) {
    float2v t;
    t.x = fexp2(fclamp(a, -30.0f, 30.0f));
    t.y = fexp2(fclamp(b, -30.0f, 30.0f));
    return t + 1.0f;
}

// y[b] = a0 + sum_k bk[k] * tanh(ck[k,:].z[b,:] + dk[k])
//
// D = mfma_32x32x16_bf16(A=s*ck, B=z, C=s*dk) -> D[node][row] = s*(dot+dk),
// s = 2*log2(e); col(lane&31)=batch row, row(reg-map)=node.
// tanh(t) = 1 - 2/(exp2(s*t)+1); 4-way shared denominator:
//   b0/t0+..+b3/t3 = [(b0t1+b1t0)t2t3 + (b2t3+b3t2)t0t1] * rcp(t0t1t2t3)
// exp2 arg clamped +-30 => 4-product <= 2^121, no overflow; clamp err ~2e-9.
//
// R9 (from R8 counters: VALUBusy=57%, HBM=9%, cold 72us vs warm 33us):
//  - 8 tiles/wave fully unrolled, ROLLING depth-4 load pipeline with
//    compile-time guards (no back-edge, no runtime load branches): loads
//    stay in flight through the whole wave body, preamble amortized 2x.
//  - Batched finalize: all 8 shfl_xor at wave end (1 lgkm drain, not 8
//    per-tile drains), then 8 predicated stores.
//  - nb pre-unpacked to float2v pairs (kills 32 unpack insts/tile).
__global__ __launch_bounds__(256) void mave_kernel(
    const float* __restrict__ z,
    const float* __restrict__ a0,
    const float* __restrict__ bk,
    const float* __restrict__ ck,
    const float* __restrict__ dk,
    float* __restrict__ out,
    int ntiles)
{
    const int lane = threadIdx.x & 63;
    const int m    = lane & 31;
    const int g    = lane >> 5;
    const float S  = 2.885390081777927f;  // 2*log2(e)

    const int wid   = (int)((blockIdx.x * blockDim.x + threadIdx.x) >> 6);
    const int tile0 = wid * 8;
    if (tile0 >= ntiles) return;
    const int tlast = ntiles - 1;

    const float* zp = z + (size_t)m * 16 + g * 8;

    // ---- issue depth-4 z loads FIRST (8x dwordx4 in flight) ----
    floatx4 zb[4][2];
    #pragma unroll
    for (int i = 0; i < 4; ++i) {
        int ti = tile0 + i; if (ti > tlast) ti = tlast;   // s_min, benign
        const float* q = zp + (size_t)ti * 512;
        zb[i][0] = *(const floatx4*)q;
        zb[i][1] = *(const floatx4*)(q + 4);
    }

    // ---- preamble overlaps the z-load latency ----
    Frag af0, af1;
    {
        const float* c0 = ck + m * 16 + g * 8;
        const float* c1 = c0 + 32 * 16;
        #pragma unroll
        for (int e = 0; e < 8; ++e) {
            af0.s[e] = f2bf(c0[e] * S);
            af1.s[e] = f2bf(c1[e] * S);
        }
    }
    floatx16 cinit0, cinit1;
    float2v  nb2[16];
    #pragma unroll
    for (int r = 0; r < 16; ++r) {
        int n = (r & 3) + 8 * (r >> 2) + 4 * g;
        cinit0[r] = S * dk[n];
        cinit1[r] = S * dk[n + 32];
        nb2[r].x = -2.0f * bk[n];
        nb2[r].y = -2.0f * bk[n + 32];
    }
    float base = a0[0];
    for (int k = 0; k < 64; ++k) base += bk[k];   // uniform -> scalar pipe

    // ---- 8 tiles, straight-line, rolling refill at distance 4 ----
    float yv[8];
    #pragma unroll
    for (int i = 0; i < 8; ++i) {
        const int s4 = i & 3;

        Frag bfr;
        bfr.d[0] = pack_bf2(zb[s4][0].x, zb[s4][0].y);
        bfr.d[1] = pack_bf2(zb[s4][0].z, zb[s4][0].w);
        bfr.d[2] = pack_bf2(zb[s4][1].x, zb[s4][1].y);
        bfr.d[3] = pack_bf2(zb[s4][1].z, zb[s4][1].w);

        if (i + 4 < 8) {                  // compile-time guard (unrolled)
            int ti = tile0 + i + 4; if (ti > tlast) ti = tlast;
            const float* q = zp + (size_t)ti * 512;
            zb[s4][0] = *(const floatx4*)q;
            zb[s4][1] = *(const floatx4*)(q + 4);
        }

        floatx16 acc0 = __builtin_amdgcn_mfma_f32_32x32x16_bf16(af0.v, bfr.v, cinit0, 0, 0, 0);
        floatx16 acc1 = __builtin_amdgcn_mfma_f32_32x32x16_bf16(af1.v, bfr.v, cinit1, 0, 0, 0);

        float2v Ya = {0.0f, 0.0f}, Yb = {0.0f, 0.0f};
        #pragma unroll
        for (int r = 0; r < 16; r += 4) {
            float2v T0 = tpair(acc0[r+0], acc1[r+0]);
            float2v T1 = tpair(acc0[r+1], acc1[r+1]);
            float2v T2 = tpair(acc0[r+2], acc1[r+2]);
            float2v T3 = tpair(acc0[r+3], acc1[r+3]);
            float2v P01 = T0 * T1, P23 = T2 * T3, P = P01 * P23;
            float2v R; R.x = frcp(P.x); R.y = frcp(P.y);
            float2v n01 = nb2[r+0] * T1 + nb2[r+1] * T0;
            float2v n23 = nb2[r+2] * T3 + nb2[r+3] * T2;
            float2v num = n01 * P23 + n23 * P01;
            if (r & 4) Yb += num * R; else Ya += num * R;
        }
        float2v Yv = Ya + Yb;
        yv[i] = Yv.x + Yv.y;
    }

    // ---- batched cross-half merge (one lgkm drain) + stores ----
    float ov[8];
    #pragma unroll
    for (int i = 0; i < 8; ++i) ov[i] = __shfl_xor(yv[i], 32, 64);
    if (g == 0) {
        #pragma unroll
        for (int i = 0; i < 8; ++i) {
            int ti = tile0 + i; if (ti > tlast) ti = tlast;
            out[(size_t)ti * 32 + m] = base + yv[i] + ov[i];
        }
    }
}

extern "C" void kernel_launch(void* const* d_in, const int* in_sizes, int n_in,
                              void* d_out, int out_size, void* d_ws, size_t ws_size,
                              hipStream_t stream) {
    const float* z  = (const float*)d_in[0];
    const float* a0 = (const float*)d_in[1];
    const float* bk = (const float*)d_in[2];
    const float* ck = (const float*)d_in[3];
    const float* dk = (const float*)d_in[4];
    float* out = (float*)d_out;

    const int B      = in_sizes[0] / 16;       // z is [B,16]
    const int ntiles = B / 32;                 // 32 batch rows per wave-tile

    // 8 tiles/wave, 4 waves/block -> 32 tiles/block; 2048 blocks at B=2M
    const int blocks = (ntiles + 31) / 32;
    hipLaunchKernelGGL(mave_kernel, dim3(blocks), dim3(256), 0, stream,
                       z, a0, bk, ck, dk, out, ntiles);
}